// Round 4
// baseline (531.627 us; speedup 1.0000x reference)
//
#include <hip/hip_runtime.h>
#include <hip/hip_bf16.h>
#include <stdint.h>
#include <stddef.h>

// Problem constants (B=4, S=2048, D_IN=D_OUT=4096, r=16, scaling/r = 1.0)
#define D_IN   4096
#define D_OUT  4096
#define M_TOT  8192
#define R_RANK 16
#define LORA_SCALE 1.0f    // SCALING / R = 16/16

typedef __attribute__((ext_vector_type(8))) short short8;    // 8 x bf16 (4 VGPRs)
typedef __attribute__((ext_vector_type(4))) short short4v;   // 4 x bf16 (2 VGPRs)
typedef __attribute__((ext_vector_type(16))) float f32x16;   // 32x32 MFMA acc

// async global->LDS, 16B per lane. LDS dest must be wave-uniform base + lane*16.
#define GL2LDS16(g, l)                                                  \
  __builtin_amdgcn_global_load_lds(                                     \
      (const __attribute__((address_space(1))) void*)(g),               \
      (__attribute__((address_space(3))) void*)(l), 16, 0, 0)

// ---------------------------------------------------------------------------
// pack_prep (fused): blocks [0, PACK_BLOCKS) convert x fp32->bf16 (8/thread);
// blocks [PACK_BLOCKS, ...) fold LoRA into W and cast. (unchanged)
// ---------------------------------------------------------------------------
#define PACK_BLOCKS 16384  // M_TOT*D_IN/(256*8)
#define PREP_BLOCKS 4096   // (D_IN/1024)*(D_OUT/4)

__global__ __launch_bounds__(256) void pack_prep(
    const float* __restrict__ x, __hip_bfloat16* __restrict__ Xp,
    const float* __restrict__ W, const float* __restrict__ A,
    const float* __restrict__ c, const float* __restrict__ B,
    __hip_bfloat16* __restrict__ Wp) {
  if (blockIdx.x < PACK_BLOCKS) {
    size_t idx = ((size_t)blockIdx.x * 256 + threadIdx.x) * 8;
    float4 v0 = *(const float4*)(x + idx);
    float4 v1 = *(const float4*)(x + idx + 4);
    __hip_bfloat16 t[8];
    t[0] = __float2bfloat16(v0.x); t[1] = __float2bfloat16(v0.y);
    t[2] = __float2bfloat16(v0.z); t[3] = __float2bfloat16(v0.w);
    t[4] = __float2bfloat16(v1.x); t[5] = __float2bfloat16(v1.y);
    t[6] = __float2bfloat16(v1.z); t[7] = __float2bfloat16(v1.w);
    *(short8*)(Xp + idx) = *(const short8*)t;
    return;
  }
  int bid = blockIdx.x - PACK_BLOCKS;
  int t  = threadIdx.x;
  int i  = (bid & 3) * 1024 + t * 4;
  int o0 = (bid >> 2) * 4;

  float4 a4[R_RANK];
#pragma unroll
  for (int r = 0; r < R_RANK; r++) {
    float4 v = *(const float4*)(A + r * D_IN + i);
    float cr = c[r] * LORA_SCALE;
    v.x *= cr; v.y *= cr; v.z *= cr; v.w *= cr;
    a4[r] = v;
  }
#pragma unroll
  for (int oo = 0; oo < 4; oo++) {
    int o = o0 + oo;
    float4 w = *(const float4*)(W + (size_t)o * D_IN + i);
#pragma unroll
    for (int r = 0; r < R_RANK; r++) {
      float br = B[o * R_RANK + r];
      w.x += br * a4[r].x; w.y += br * a4[r].y;
      w.z += br * a4[r].z; w.w += br * a4[r].w;
    }
    __hip_bfloat16 tb[4];
    tb[0] = __float2bfloat16(w.x); tb[1] = __float2bfloat16(w.y);
    tb[2] = __float2bfloat16(w.z); tb[3] = __float2bfloat16(w.w);
    *(short4v*)(Wp + (size_t)o * D_IN + i) = *(const short4v*)tb;
  }
}

// ---------------------------------------------------------------------------
// gemm_256: 256x256 tile, BK=64, 512 threads (8 waves, 2Mx4N), 8-phase
// schedule with counted vmcnt (T3+T4), setprio (T5), 32x32x16 MFMA
// (fragment mapping verified round 2).
//
// THIS ROUND: restore round-1's measured-zero-conflict LDS bank geometry
// under the 32x32 readers. Round 3's K-half blocks ([256][32], 64B row
// stride, 4-chunk XOR) measured 2.5e7 bank conflicts (~190 cyc/phase).
// Now: smem[buf][A|B][256 rows][64 bf16] -- 128B row stride (== 0 mod 32
// banks) with 8-chunk swizzle phys = log ^ (row&7), exactly the pattern
// that measured 0.0 conflicts in round 1. Swizzle applied to the GLOBAL
// source column; LDS deposit stays linear (rule #21).
//
// Staging granularity: 64-row issues (512 thr x 16B = 8KiB), 8 per tile
// (A0..A3, B0..B3). Issue order while computing tile t (staging t+1):
//   ph0: B0,B1   ph1: B2,B3   ph2: A0,A2   ph3: A1,A3
// Consumption at tile t+1: ph0 reads B0..B3 + A0,A2 (rows 0..63/128..191
// per wm); ph1 reads A1,A3 (rows 64..127/192..255). So:
//   ph0-end: vmcnt(2)  -- retires prev tile's A1,A3 before ph1 reads them
//            (outstanding there: {A1,A3,B0',B1'} = 4 -> keep 2 newest)
//   ph3-end: vmcnt(2)  -- retires B0..B3,A0,A2 before next ph0; keeps A1,A3
// Counted waits only; never drained to 0 in the main loop.
// ---------------------------------------------------------------------------
#define BK 64
#define NT (D_IN / BK)  // 64

// bf16-element offset of block (buf, A|B): each block 256*64 = 16384 elems
#define SOFF(BUFI, AB) (((BUFI) * 2 + (AB)) * 16384)

#define VMCNT(N) asm volatile("s_waitcnt vmcnt(" #N ")" ::: "memory")
#define HARD_BARRIER() asm volatile("s_barrier" ::: "memory")
#define SOFT_BARRIER() __builtin_amdgcn_s_barrier()

// stage one 64-row issue (8 KiB) of tile TS into block (BUFI,AB), rows
// [ISS*64, ISS*64+64). One gload_lds(16B)/thread; LDS deposit linear
// (tid*16B); global col pre-swizzled: cc = (tid&7) ^ (row&7).
#define STAGE_ISSUE(BUFI, AB, ISS, TS)                                       \
  do {                                                                       \
    const __hip_bfloat16* _src = (AB) ? Wp : Xp;                             \
    const int _rb = (AB) ? n0 : m0;                                          \
    const int _rl = tid >> 3;           /* row 0..63 within issue */         \
    const int _cc = (tid & 7) ^ (_rl & 7);                                   \
    GL2LDS16(_src + (size_t)(_rb + (ISS) * 64 + _rl) * D_IN + (TS) * BK +    \
                 _cc * 8,                                                    \
             smem + SOFF(BUFI, AB) + (ISS) * 4096 + tid * 8);                \
  } while (0)

// af[i]: i = kfh*2 + r. row = wm*128 + (RH*2+r)*32 + l31 (base %32==0 so
// row&7 = l31&7 = x7). logical chunk = H*4 + kfh*2 + lh; physical = ^x7.
#define LOAD_AF(BUFI, H, RH)                                                 \
  _Pragma("unroll")                                                          \
  for (int _i = 0; _i < 4; ++_i)                                             \
    af[_i] = *(const short8*)(smem + SOFF(BUFI, 0) +                         \
                              (wm * 128 + ((RH) * 2 + (_i & 1)) * 32 + l31)  \
                                  * 64 +                                     \
                              (((H) * 4 + (_i >> 1) * 2 + lh) ^ x7) * 8);

// bf[i]: i = kfh*2 + nb. row = wn*64 + nb*32 + l31.
#define LOAD_BF(BUFI, H)                                                     \
  _Pragma("unroll")                                                          \
  for (int _i = 0; _i < 4; ++_i)                                             \
    bf[_i] = *(const short8*)(smem + SOFF(BUFI, 1) +                         \
                              (wn * 64 + (_i & 1) * 32 + l31) * 64 +         \
                              (((H) * 4 + (_i >> 1) * 2 + lh) ^ x7) * 8);

// 8 MFMA: (rb = RH*2 + r) x nb x kfh; kfh outer -> 4 independent accs
// between same-acc reuses.
#define MFMA_QUAD(RH)                                                        \
  do {                                                                       \
    __builtin_amdgcn_s_setprio(1);                                           \
    _Pragma("unroll")                                                        \
    for (int _kfh = 0; _kfh < 2; ++_kfh)                                     \
      _Pragma("unroll")                                                      \
      for (int _r = 0; _r < 2; ++_r)                                         \
        _Pragma("unroll")                                                    \
        for (int _n = 0; _n < 2; ++_n)                                       \
          acc[(RH) * 2 + _r][_n] = __builtin_amdgcn_mfma_f32_32x32x16_bf16(  \
              af[_kfh * 2 + _r], bf[_kfh * 2 + _n],                          \
              acc[(RH) * 2 + _r][_n], 0, 0, 0);                              \
    __builtin_amdgcn_s_setprio(0);                                           \
  } while (0)

// DO_STAGE is a compile-time literal 0/1.
#define TILE_BODY(BUFI, NBUF, T, DO_STAGE)                                   \
  do {                                                                       \
    /* ph0: K-half0, rb{0,1}; stage B0,B1 */                                 \
    LOAD_AF(BUFI, 0, 0);                                                     \
    LOAD_BF(BUFI, 0);                                                        \
    if (DO_STAGE) {                                                          \
      STAGE_ISSUE(NBUF, 1, 0, (T) + 1);                                      \
      STAGE_ISSUE(NBUF, 1, 1, (T) + 1);                                      \
    }                                                                        \
    SOFT_BARRIER();                                                          \
    MFMA_QUAD(0);                                                            \
    if (DO_STAGE) { VMCNT(2); } else { VMCNT(0); }                           \
    HARD_BARRIER();                                                          \
    /* ph1: K-half0, rb{2,3}; stage B2,B3 */                                 \
    LOAD_AF(BUFI, 0, 1);                                                     \
    if (DO_STAGE) {                                                          \
      STAGE_ISSUE(NBUF, 1, 2, (T) + 1);                                      \
      STAGE_ISSUE(NBUF, 1, 3, (T) + 1);                                      \
    }                                                                        \
    SOFT_BARRIER();                                                          \
    MFMA_QUAD(1);                                                            \
    SOFT_BARRIER();                                                          \
    /* ph2: K-half1, rb{0,1}; stage A0,A2 */                                 \
    LOAD_AF(BUFI, 1, 0);                                                     \
    LOAD_BF(BUFI, 1);                                                        \
    if (DO_STAGE) {                                                          \
      STAGE_ISSUE(NBUF, 0, 0, (T) + 1);                                      \
      STAGE_ISSUE(NBUF, 0, 2, (T) + 1);                                      \
    }                                                                        \
    SOFT_BARRIER();                                                          \
    MFMA_QUAD(0);                                                            \
    SOFT_BARRIER();                                                          \
    /* ph3: K-half1, rb{2,3}; stage A1,A3 (newest 2 = excluded by vmcnt) */  \
    LOAD_AF(BUFI, 1, 1);                                                     \
    if (DO_STAGE) {                                                          \
      STAGE_ISSUE(NBUF, 0, 1, (T) + 1);                                      \
      STAGE_ISSUE(NBUF, 0, 3, (T) + 1);                                      \
    }                                                                        \
    SOFT_BARRIER();                                                          \
    MFMA_QUAD(1);                                                            \
    if (DO_STAGE) { VMCNT(2); } else { VMCNT(0); }                           \
    HARD_BARRIER();                                                          \
  } while (0)

__global__ __launch_bounds__(512, 2) void gemm_256(
    const __hip_bfloat16* __restrict__ Xp,
    const __hip_bfloat16* __restrict__ Wp,
    const float* __restrict__ bias,
    float* __restrict__ out) {
  // 2 bufs x {A,B} x 256x64 bf16 = 128 KiB (1 block/CU)
  __shared__ __align__(16) __hip_bfloat16 smem[2 * 2 * 16384];

  const int tid  = threadIdx.x;
  const int wid  = tid >> 6;
  const int lane = tid & 63;
  const int wm = wid >> 2;            // 0..1  (M half: 128 rows)
  const int wn = wid & 3;             // 0..3  (N quarter: 64 cols)
  const int l31 = lane & 31;
  const int lh  = lane >> 5;          // 0..1
  const int x7  = l31 & 7;            // 8-chunk swizzle term (= row&7)
  const int m0 = blockIdx.y * 256;
  const int n0 = blockIdx.x * 256;

  f32x16 acc[4][2];
#pragma unroll
  for (int i = 0; i < 4; i++)
#pragma unroll
    for (int j = 0; j < 2; j++)
#pragma unroll
      for (int k = 0; k < 16; k++) acc[i][j][k] = 0.f;

  short8 af[4];
  short8 bf[4];

  // Prologue: stage tile 0 -> buf0 in steady-state order (A1,A3 newest).
  STAGE_ISSUE(0, 1, 0, 0);
  STAGE_ISSUE(0, 1, 1, 0);
  STAGE_ISSUE(0, 1, 2, 0);
  STAGE_ISSUE(0, 1, 3, 0);
  STAGE_ISSUE(0, 0, 0, 0);
  STAGE_ISSUE(0, 0, 2, 0);
  STAGE_ISSUE(0, 0, 1, 0);
  STAGE_ISSUE(0, 0, 3, 0);
  VMCNT(2);                // all but A1,A3 landed (matches steady state)
  HARD_BARRIER();

#pragma unroll 1
  for (int t = 0; t < NT - 2; t += 2) {
    TILE_BODY(0, 1, t, 1);       // compute buf0 (tile t),   stage t+1 -> buf1
    TILE_BODY(1, 0, t + 1, 1);   // compute buf1 (tile t+1), stage t+2 -> buf0
  }
  TILE_BODY(0, 1, NT - 2, 1);    // tile 62, stages tile 63 -> buf1
  TILE_BODY(1, 0, NT - 1, 0);    // tile 63, epilogue (drains with vmcnt(0))

  // Epilogue: 32x32 C/D: col = lane&31, row = (reg&3)+8*(reg>>2)+4*(lane>>5)
  float bv[2];
#pragma unroll
  for (int nb = 0; nb < 2; ++nb) bv[nb] = bias[n0 + wn * 64 + nb * 32 + l31];
#pragma unroll
  for (int rb = 0; rb < 4; ++rb) {
#pragma unroll
    for (int r = 0; r < 16; ++r) {
      const int row = m0 + wm * 128 + rb * 32 + (r & 3) + 8 * (r >> 2) + 4 * lh;
      float* po = out + (size_t)row * D_OUT + n0 + wn * 64 + l31;
      po[0]  = acc[rb][0][r] + bv[0];
      po[32] = acc[rb][1][r] + bv[1];
    }
  }
}

// ---------------------------------------------------------------------------
extern "C" void kernel_launch(void* const* d_in, const int* in_sizes, int n_in,
                              void* d_out, int out_size, void* d_ws, size_t ws_size,
                              hipStream_t stream) {
  const float* x  = (const float*)d_in[0];   // [4,2048,4096]
  const float* W  = (const float*)d_in[1];   // [4096,4096]
  const float* b  = (const float*)d_in[2];   // [4096]
  const float* lA = (const float*)d_in[3];   // [16,4096]
  const float* lB = (const float*)d_in[4];   // [4096,16]
  const float* lc = (const float*)d_in[5];   // [16,1]
  float* out = (float*)d_out;                // [4,2048,4096] fp32

  char* ws = (char*)d_ws;
  __hip_bfloat16* Xp = (__hip_bfloat16*)ws;                       // 64 MiB
  __hip_bfloat16* Wp = (__hip_bfloat16*)(ws + (size_t)67108864);  // 32 MiB

  pack_prep<<<dim3(PACK_BLOCKS + PREP_BLOCKS), dim3(256), 0, stream>>>(
      x, Xp, W, lA, lc, lB, Wp);
  gemm_256<<<dim3(D_OUT / 256, M_TOT / 256), dim3(512), 0, stream>>>(Xp, Wp, b, out);
}

// Round 5
// 506.595 us; speedup vs baseline: 1.0494x; 1.0494x over previous
//
#include <hip/hip_runtime.h>
#include <hip/hip_bf16.h>
#include <stdint.h>
#include <stddef.h>

// Problem constants (B=4, S=2048, D_IN=D_OUT=4096, r=16, scaling/r = 1.0)
#define D_IN   4096
#define D_OUT  4096
#define M_TOT  8192
#define R_RANK 16
#define LORA_SCALE 1.0f    // SCALING / R = 16/16

typedef __attribute__((ext_vector_type(8))) short short8;   // 8 x bf16 (4 VGPRs)
typedef __attribute__((ext_vector_type(4))) short short4v;  // 4 x bf16 (2 VGPRs)
typedef __attribute__((ext_vector_type(4))) float f32x4;    // MFMA accumulator

// async global->LDS, 16B per lane. LDS dest must be wave-uniform base + lane*16.
#define GL2LDS16(g, l)                                                  \
  __builtin_amdgcn_global_load_lds(                                     \
      (const __attribute__((address_space(1))) void*)(g),               \
      (__attribute__((address_space(3))) void*)(l), 16, 0, 0)

// ---------------------------------------------------------------------------
// pack_prep (fused): blocks [0, PACK_BLOCKS) convert x fp32->bf16 (8/thread);
// blocks [PACK_BLOCKS, ...) fold LoRA into W and cast. (unchanged)
// ---------------------------------------------------------------------------
#define PACK_BLOCKS 16384  // M_TOT*D_IN/(256*8)
#define PREP_BLOCKS 4096   // (D_IN/1024)*(D_OUT/4)

__global__ __launch_bounds__(256) void pack_prep(
    const float* __restrict__ x, __hip_bfloat16* __restrict__ Xp,
    const float* __restrict__ W, const float* __restrict__ A,
    const float* __restrict__ c, const float* __restrict__ B,
    __hip_bfloat16* __restrict__ Wp) {
  if (blockIdx.x < PACK_BLOCKS) {
    size_t idx = ((size_t)blockIdx.x * 256 + threadIdx.x) * 8;
    float4 v0 = *(const float4*)(x + idx);
    float4 v1 = *(const float4*)(x + idx + 4);
    __hip_bfloat16 t[8];
    t[0] = __float2bfloat16(v0.x); t[1] = __float2bfloat16(v0.y);
    t[2] = __float2bfloat16(v0.z); t[3] = __float2bfloat16(v0.w);
    t[4] = __float2bfloat16(v1.x); t[5] = __float2bfloat16(v1.y);
    t[6] = __float2bfloat16(v1.z); t[7] = __float2bfloat16(v1.w);
    *(short8*)(Xp + idx) = *(const short8*)t;
    return;
  }
  int bid = blockIdx.x - PACK_BLOCKS;
  int t  = threadIdx.x;
  int i  = (bid & 3) * 1024 + t * 4;
  int o0 = (bid >> 2) * 4;

  float4 a4[R_RANK];
#pragma unroll
  for (int r = 0; r < R_RANK; r++) {
    float4 v = *(const float4*)(A + r * D_IN + i);
    float cr = c[r] * LORA_SCALE;
    v.x *= cr; v.y *= cr; v.z *= cr; v.w *= cr;
    a4[r] = v;
  }
#pragma unroll
  for (int oo = 0; oo < 4; oo++) {
    int o = o0 + oo;
    float4 w = *(const float4*)(W + (size_t)o * D_IN + i);
#pragma unroll
    for (int r = 0; r < R_RANK; r++) {
      float br = B[o * R_RANK + r];
      w.x += br * a4[r].x; w.y += br * a4[r].y;
      w.z += br * a4[r].z; w.w += br * a4[r].w;
    }
    __hip_bfloat16 tb[4];
    tb[0] = __float2bfloat16(w.x); tb[1] = __float2bfloat16(w.y);
    tb[2] = __float2bfloat16(w.z); tb[3] = __float2bfloat16(w.w);
    *(short4v*)(Wp + (size_t)o * D_IN + i) = *(const short4v*)tb;
  }
}

// ---------------------------------------------------------------------------
// gemm_256: ROUND-1 VERBATIM (measured: 239 us, MfmaUtil 53, conflicts 0.0)
// — 256x256 tile, BK=64, 512 threads (8 waves 2Mx4N), 16x16x32 MFMA,
// 8-phase schedule with counted vmcnt, setprio, [256][32] K-half LDS blocks
// with 4-chunk XOR swizzle applied to the global source (rule #21).
// The 32x32-MFMA arc (rounds 2-4) is abandoned: two independent bank
// geometries both measured 2.517e7 conflicts (model falsified twice);
// empirically 16x16 at 239 us beats every 32x32 variant (272+ us).
//
// THIS ROUND'S ONLY CHANGE: T1 bijective XCD swizzle. 512 workgroups
// (512%8==0): XCD x owns logical tiles [x*64, x*64+64) = 4 complete M-rows
// x 16 N-tiles. The 16 consecutive tiles sharing a 2MB Xp A-panel become
// co-resident on one XCD's 4MB L2 instead of spread over 8 XCDs
// (FETCH_SIZE measured 300MB vs 96MB of inputs = ~3x A-panel re-fetch).
// ---------------------------------------------------------------------------
#define BM 256
#define BN 256
#define BK 64
#define NT (D_IN / BK)  // 64

#define SOFF(BUFI, AB, KH) ((((BUFI) * 2 + (AB)) * 2 + (KH)) * 8192)

#define VMCNT(N) asm volatile("s_waitcnt vmcnt(" #N ")" ::: "memory")
#define HARD_BARRIER() asm volatile("s_barrier" ::: "memory")
#define SOFT_BARRIER() __builtin_amdgcn_s_barrier()

// stage one half-tile (256 rows x 32 cols bf16 = 16KiB) of tile TS into
// smem block (BUFI, AB, KH). 2 x global_load_lds(16B) per thread.
#define STAGE_HALF(BUFI, AB, KH, TS)                                         \
  do {                                                                       \
    const __hip_bfloat16* _src = (AB) ? Wp : Xp;                             \
    const int _rb = (AB) ? n0 : m0;                                          \
    const int _kb = (TS) * BK + (KH) * 32;                                   \
    _Pragma("unroll")                                                        \
    for (int _is = 0; _is < 2; ++_is) {                                      \
      const int _p = _is * 512 + tid;   /* chunk 0..1023 */                  \
      const int _row = _p >> 2;                                              \
      const int _c = (_p & 3) ^ ((_row >> 1) & 3); /* inverse swizzle */     \
      GL2LDS16(_src + (size_t)(_rb + _row) * D_IN + _kb + _c * 8,            \
               smem + SOFF(BUFI, AB, KH) + _p * 8);                          \
    }                                                                        \
  } while (0)

#define LOAD_AF(BUFI, H, MH)                                                 \
  _Pragma("unroll")                                                          \
  for (int _j = 0; _j < 4; ++_j)                                             \
    af[_j] = *(const short8*)(smem + SOFF(BUFI, 0, H) +                      \
                              (wm * 128 + ((MH) * 4 + _j) * 16 + l15) * 32 + \
                              cph * 8);

#define LOAD_BF(BUFI, H)                                                     \
  _Pragma("unroll")                                                          \
  for (int _nn = 0; _nn < 4; ++_nn)                                          \
    bf[_nn] = *(const short8*)(smem + SOFF(BUFI, 1, H) +                     \
                               (wn * 64 + _nn * 16 + l15) * 32 + cph * 8);

#define MFMA_HALF(MH)                                                        \
  do {                                                                       \
    __builtin_amdgcn_s_setprio(1);                                           \
    _Pragma("unroll")                                                        \
    for (int _j = 0; _j < 4; ++_j)                                           \
      _Pragma("unroll")                                                      \
      for (int _nn = 0; _nn < 4; ++_nn)                                      \
        acc[(MH) * 4 + _j][_nn] = __builtin_amdgcn_mfma_f32_16x16x32_bf16(   \
            af[_j], bf[_nn], acc[(MH) * 4 + _j][_nn], 0, 0, 0);              \
    __builtin_amdgcn_s_setprio(0);                                           \
  } while (0)

// DO_STAGE is a compile-time literal 0/1.
#define TILE_BODY(BUFI, NBUF, T, DO_STAGE)                                   \
  do {                                                                       \
    /* ph0: kh=0, mh=0 */                                                    \
    LOAD_AF(BUFI, 0, 0);                                                     \
    LOAD_BF(BUFI, 0);                                                        \
    if (DO_STAGE) STAGE_HALF(NBUF, 0, 0, (T) + 1);                           \
    SOFT_BARRIER();                                                          \
    MFMA_HALF(0);                                                            \
    SOFT_BARRIER();                                                          \
    /* ph1: kh=0, mh=1 */                                                    \
    LOAD_AF(BUFI, 0, 1);                                                     \
    if (DO_STAGE) STAGE_HALF(NBUF, 1, 0, (T) + 1);                           \
    SOFT_BARRIER();                                                          \
    MFMA_HALF(1);                                                            \
    if (DO_STAGE) { VMCNT(4); } else { VMCNT(0); }                           \
    HARD_BARRIER();                                                          \
    /* ph2: kh=1, mh=0 */                                                    \
    LOAD_AF(BUFI, 1, 0);                                                     \
    LOAD_BF(BUFI, 1);                                                        \
    if (DO_STAGE) STAGE_HALF(NBUF, 0, 1, (T) + 1);                           \
    SOFT_BARRIER();                                                          \
    MFMA_HALF(0);                                                            \
    SOFT_BARRIER();                                                          \
    /* ph3: kh=1, mh=1 */                                                    \
    LOAD_AF(BUFI, 1, 1);                                                     \
    if (DO_STAGE) STAGE_HALF(NBUF, 1, 1, (T) + 1);                           \
    SOFT_BARRIER();                                                          \
    MFMA_HALF(1);                                                            \
    if (DO_STAGE) { VMCNT(4); } else { VMCNT(0); }                           \
    HARD_BARRIER();                                                          \
  } while (0)

__global__ __launch_bounds__(512, 2) void gemm_256(
    const __hip_bfloat16* __restrict__ Xp,
    const __hip_bfloat16* __restrict__ Wp,
    const float* __restrict__ bias,
    float* __restrict__ out) {
  // 2 bufs x {A,B} x {kh0,kh1} x 256x32 bf16 = 128 KiB (1 block/CU)
  __shared__ __align__(16) __hip_bfloat16 smem[2 * 2 * 2 * 8192];

  const int tid  = threadIdx.x;
  const int wid  = tid >> 6;
  const int lane = tid & 63;
  const int wm = wid >> 2;            // 0..1  (M half: 128 rows)
  const int wn = wid & 3;             // 0..3  (N quarter: 64 cols)
  const int l15 = lane & 15;
  const int kg  = lane >> 4;          // 0..3
  const int cph = kg ^ ((l15 >> 1) & 3);  // swizzled read chunk (const/thread)

  // T1 bijective XCD swizzle: 512 wgs, dispatch round-robins XCDs (bid&7);
  // give XCD x the contiguous logical chunk [x*64, x*64+64) = 4 M-rows x 16.
  const int bid  = (int)blockIdx.x;
  const int lbid = (bid & 7) * 64 + (bid >> 3);
  const int m0 = (lbid >> 4) * BM;    // 32 M-tiles
  const int n0 = (lbid & 15) * BN;    // 16 N-tiles

  f32x4 acc[8][4];
#pragma unroll
  for (int i = 0; i < 8; i++)
#pragma unroll
    for (int j = 0; j < 4; j++) acc[i][j] = (f32x4){0.f, 0.f, 0.f, 0.f};

  short8 af[4];
  short8 bf[4];

  // Prologue: stage tile 0 -> buf0, consumption-priority order.
  STAGE_HALF(0, 0, 0, 0);  // A kh0
  STAGE_HALF(0, 1, 0, 0);  // B kh0
  STAGE_HALF(0, 0, 1, 0);  // A kh1
  STAGE_HALF(0, 1, 1, 0);  // B kh1
  VMCNT(4);                // A/B kh0 landed; kh1 still in flight
  HARD_BARRIER();

#pragma unroll 1
  for (int t = 0; t < NT - 2; t += 2) {
    TILE_BODY(0, 1, t, 1);       // compute buf0 (tile t),   stage t+1 -> buf1
    TILE_BODY(1, 0, t + 1, 1);   // compute buf1 (tile t+1), stage t+2 -> buf0
  }
  TILE_BODY(0, 1, NT - 2, 1);    // tile 62, stages tile 63 -> buf1
  TILE_BODY(1, 0, NT - 1, 0);    // tile 63, epilogue (drain with vmcnt(0))

  // Epilogue: C/D layout col = lane&15 (n), row = (lane>>4)*4+reg (m); + bias
  float bv[4];
#pragma unroll
  for (int nn = 0; nn < 4; ++nn) bv[nn] = bias[n0 + wn * 64 + nn * 16 + l15];
#pragma unroll
  for (int mm = 0; mm < 8; ++mm) {
#pragma unroll
    for (int reg = 0; reg < 4; ++reg) {
      const int row = m0 + wm * 128 + mm * 16 + kg * 4 + reg;
      float* po = out + (size_t)row * D_OUT + n0 + wn * 64 + l15;
#pragma unroll
      for (int nn = 0; nn < 4; ++nn) po[nn * 16] = acc[mm][nn][reg] + bv[nn];
    }
  }
}

// ---------------------------------------------------------------------------
extern "C" void kernel_launch(void* const* d_in, const int* in_sizes, int n_in,
                              void* d_out, int out_size, void* d_ws, size_t ws_size,
                              hipStream_t stream) {
  const float* x  = (const float*)d_in[0];   // [4,2048,4096]
  const float* W  = (const float*)d_in[1];   // [4096,4096]
  const float* b  = (const float*)d_in[2];   // [4096]
  const float* lA = (const float*)d_in[3];   // [16,4096]
  const float* lB = (const float*)d_in[4];   // [4096,16]
  const float* lc = (const float*)d_in[5];   // [16,1]
  float* out = (float*)d_out;                // [4,2048,4096] fp32

  char* ws = (char*)d_ws;
  __hip_bfloat16* Xp = (__hip_bfloat16*)ws;                       // 64 MiB
  __hip_bfloat16* Wp = (__hip_bfloat16*)(ws + (size_t)67108864);  // 32 MiB

  pack_prep<<<dim3(PACK_BLOCKS + PREP_BLOCKS), dim3(256), 0, stream>>>(
      x, Xp, W, lA, lc, lB, Wp);
  gemm_256<<<dim3((M_TOT / BM) * (D_OUT / BN)), dim3(512), 0, stream>>>(
      Xp, Wp, b, out);
}